// Round 13
// baseline (1404.895 us; speedup 1.0000x reference)
//
#include <hip/hip_runtime.h>
#include <math.h>

#define HH 128
#define WW 128
#define CIN 512
#define NPIX 16384
#define NPRE 6000
#define NPOST 300
#define NMW 94          // u64 words per mask row: ceil(6000/64)

// workspace offsets (floats; LOG region doubles, MASK region u64, 8B-aligned)
#define WS_WT     0ull                        // 2359296 floats (f32 wt2)
#define WS_LIST   2359296ull                  // 16384 ints
#define WS_NACT   2375680ull                  // 1 int
#define WS_MASK   2375684ull                  // 6000*94 u64 = 1128000 floats
#define WS_LOG    4718592ull                  // 16384*12 doubles
#define WS_ROI    5160960ull                  // 16384*4
#define WS_SC32   5226496ull                  // 16384
#define WS_CAND   5242880ull                  // 6000*4
#define WS_TOPS   5266880ull                  // 6000

// d_out offsets (floats), concatenated tuple in return order
#define O_LOCS   0
#define O_ROIS   65536
#define O_RIDX   66736
#define O_ANCHOR 67036
#define O_CLS    132572
#define O_COS    247260
#define O_RSC    263644
#define O_OLD    263944

typedef double d4 __attribute__((ext_vector_type(4)));

__device__ __forceinline__ float exp32(float x) { return (float)exp((double)x); }
__device__ __forceinline__ float sqrt32(float x) { return (float)sqrt((double)x); }

// ---- fused prep: blocks 0..575 wt transpose+permute; 576..1022 zero logits;
// ---- block 1023 builds the compacted active-pixel list ----------------------
__global__ __launch_bounds__(256) void prep_kernel(
    const float* __restrict__ w, float* __restrict__ wt2,
    double* __restrict__ logits, const int* __restrict__ mask,
    int* __restrict__ list, int* __restrict__ nact) {
  int b = blockIdx.x;
  int tid = threadIdx.x;
  if (b < 576) {
    // wt: w[m][c][k] (f32) -> wt2[(c*9+k)][g*64 + (m%16)*4 + m/16]
    __shared__ float t[64][65];
    int ck0 = (b % 72) * 64;
    int m0  = (b / 72) * 64;
    int j  = tid & 63;
    int i0 = tid >> 6;
#pragma unroll
    for (int ii = 0; ii < 16; ++ii) {
      int i = i0 + ii * 4;
      t[i][j] = w[(size_t)(m0 + i) * 4608 + ck0 + j];
    }
    __syncthreads();
    int jp = ((j & 15) << 2) | (j >> 4);
#pragma unroll
    for (int ii = 0; ii < 16; ++ii) {
      int jj = i0 + ii * 4;
      wt2[(size_t)(ck0 + jj) * 512 + m0 + jp] = t[j][jj];
    }
  } else if (b < 1023) {
    // zero logits: 196608 doubles, grid-stride over 447 blocks
    int i = (b - 576) * 256 + tid;
    const int stride = 447 * 256;
    for (; i < NPIX * 12; i += stride) logits[i] = 0.0;
  } else {
    // alist: deterministic row-major compaction, 256 threads x 64 pixels
    __shared__ int sc[256];
    int base = tid << 6;
    int cnt = 0;
    for (int i = 0; i < 64; ++i) cnt += (mask[base + i] != 0);
    sc[tid] = cnt;
    __syncthreads();
    for (int off = 1; off < 256; off <<= 1) {
      int v = 0;
      if (tid >= off) v = sc[tid - off];
      __syncthreads();
      sc[tid] += v;
      __syncthreads();
    }
    int pos = sc[tid] - cnt;
    for (int i = 0; i < 64; ++i)
      if (mask[base + i] != 0) list[pos++] = base + i;
    if (tid == 255) nact[0] = sc[255];
  }
}

__device__ __forceinline__ void conv_comp4(const float* raws, const float4* bvs,
                                           const bool* valj, d4* acc) {
#pragma unroll
  for (int j = 0; j < 9; ++j) {
    float av = valj[j] ? raws[j] : 0.f;
    double a = (double)av;
    acc[0] = __builtin_amdgcn_mfma_f64_16x16x4f64(a, (double)bvs[j].x, acc[0], 0, 0, 0);
    acc[1] = __builtin_amdgcn_mfma_f64_16x16x4f64(a, (double)bvs[j].y, acc[1], 0, 0, 0);
    acc[2] = __builtin_amdgcn_mfma_f64_16x16x4f64(a, (double)bvs[j].z, acc[2], 0, 0, 0);
    acc[3] = __builtin_amdgcn_mfma_f64_16x16x4f64(a, (double)bvs[j].w, acc[3], 0, 0, 0);
  }
}

// ------- implicit-GEMM conv via fp64 MFMA 16x16x4 + fused heads --------------
// R9 exact structure (plateau: 918us, 57.6% MfmaUtil across 7 variants).
__global__ __launch_bounds__(256, 2) void conv_mfma_kernel(
    const float* __restrict__ x, const float* __restrict__ wt2,
    const float* __restrict__ bias, const float* __restrict__ loc_w,
    const float* __restrict__ cls_w, const float* __restrict__ cos_w,
    const int* __restrict__ list, const int* __restrict__ nact,
    double* __restrict__ logits) {
  int tid = threadIdx.x;
  int lane = tid & 63;
  int wv = tid >> 6;                  // wave 0..3
  int n = nact[0];
  int ntg = (n + 63) >> 6;            // active tile-groups (4 x 16-pixel tiles)
  int total = ntg << 3;               // work items: tile-major (w = tg*8 + g)
  int lin = blockIdx.x;
  int xcd = lin & 7;
  int slot = lin >> 3;
  int wpx = (total + 7) >> 3;         // work items per XCD
  int w = xcd * wpx + slot;
  if (slot >= wpx || w >= total) return;   // block-uniform exit
  int tg = w >> 3;                    // tile-group (contiguous range per XCD)
  int m0 = (w & 7) << 6;              // outch group base
  int tile = tg * 4 + wv;             // 16-pixel tile
  if (tile * 16 >= n) return;         // tail: wave-uniform exit, no barriers
  int col = lane & 15;
  int kk = lane >> 4;

  // --- probe the D layout: rowmap[r], colmap[r] per lane register ---
  d4 zz = (d4){0.0, 0.0, 0.0, 0.0};
  double pa1 = (kk == 0) ? (double)col : 0.0;   // A[m][0] = m
  double pb1 = (kk == 0) ? 1.0 : 0.0;           // B[0][n] = 1
  d4 rp = __builtin_amdgcn_mfma_f64_16x16x4f64(pa1, pb1, zz, 0, 0, 0);
  double pa2 = (kk == 0) ? 1.0 : 0.0;           // A[m][0] = 1
  double pb2 = (kk == 0) ? (double)col : 0.0;   // B[0][n] = n
  d4 cp = __builtin_amdgcn_mfma_f64_16x16x4f64(pa2, pb2, zz, 0, 0, 0);
  int rowmap[4], colmap[4];
#pragma unroll
  for (int r = 0; r < 4; ++r) {
    rowmap[r] = (int)rp[r];
    colmap[r] = (int)cp[r];
  }

  int slotp = tile * 16 + col;        // A-row pixel for this lane
  int p = (slotp < n) ? list[slotp] : -1;
  bool pv = (p >= 0);
  int py = p >> 7, px = p & 127;

  // per-lane tap offsets + validity, hoisted out of the K loop
  int offj[9];
  bool valj[9];
#pragma unroll
  for (int j = 0; j < 9; ++j) {
    int dy = j / 3 - 1, dx = j % 3 - 1;
    int yy = py + dy, xx = px + dx;
    bool v = pv && (yy >= 0) && (yy < HH) && (xx >= 0) && (xx < WW);
    valj[j] = v;
    offj[j] = v ? (yy * WW + xx) : 0;
  }

  d4 acc[4];
#pragma unroll
  for (int nf = 0; nf < 4; ++nf) acc[nf] = (d4){0.0, 0.0, 0.0, 0.0};

  const float* xk = x + (size_t)kk * NPIX;
  const float* wk = wt2 + (size_t)(kk * 9) * 512 + m0 + (col << 2);

  for (int c0 = 0; c0 < CIN; c0 += 8) {
    const float* xc0 = xk + (size_t)c0 * NPIX;
    const float* xc1 = xc0 + (size_t)4 * NPIX;
    const float* wc0 = wk + (size_t)c0 * 4608;   // c0*9*512
    const float* wc1 = wc0 + 4 * 4608;
    float raws[18];
    float4 bvs[18];
#pragma unroll
    for (int j = 0; j < 9; ++j) {
      raws[j] = xc0[offj[j]];
      raws[9 + j] = xc1[offj[j]];
      bvs[j] = *(const float4*)(wc0 + j * 512);
      bvs[9 + j] = *(const float4*)(wc1 + j * 512);
    }
    conv_comp4(raws, bvs, valj, acc);
    conv_comp4(raws + 9, bvs + 9, valj, acc);
  }

#pragma unroll
  for (int jj = 0; jj < 4; ++jj) {
    int cm = colmap[jj];
    float hvj[4];
#pragma unroll
    for (int nf = 0; nf < 4; ++nf) {
      float bb = bias[m0 + nf * 16 + cm];
      hvj[nf] = fmaxf(__fadd_rn((float)acc[nf][jj], bb), 0.f);
    }
    int s2 = tile * 16 + rowmap[jj];
    bool wr = (col == 0) && (s2 < n);
    int pix = wr ? list[s2] : 0;
#pragma unroll
    for (int r = 0; r < 12; ++r) {
      double t = 0.0;
#pragma unroll
      for (int nf = 0; nf < 4; ++nf) {
        int oc = m0 + nf * 16 + cm;
        float wh = (r < 4) ? loc_w[r * 512 + oc]
                           : (r < 11) ? cls_w[(r - 4) * 512 + oc] : cos_w[oc];
        t += (double)hvj[nf] * (double)wh;
      }
#pragma unroll
      for (int o = 8; o; o >>= 1) t += __shfl_xor(t, o, 16);
      if (wr) atomicAdd(&logits[(size_t)pix * 12 + r], t);
    }
  }
}

// ---- fused finalize+roi: per-pixel f64 softmax/argmax/sigmoid + anchors,
// ---- loc2bbox, clip, validity, scores. Pixel-0's cos/ascale recomputed
// ---- redundantly per thread (same f32 casts as the split version). ----------
__global__ __launch_bounds__(256) void finroi_kernel(
    const double* __restrict__ logits, const float* __restrict__ loc_b,
    const float* __restrict__ cls_b, const float* __restrict__ cos_b,
    const int* __restrict__ img_h, const int* __restrict__ img_w,
    float* __restrict__ out, float* __restrict__ roi,
    float* __restrict__ scores32) {
  int p = blockIdx.x * 256 + threadIdx.x;
  const double* lg = &logits[(size_t)p * 12];
  // ---- finalize(p) ----
  float l4[4];
#pragma unroll
  for (int o = 0; o < 4; ++o) {
    l4[o] = (float)(lg[o] + (double)loc_b[o]);
    out[O_LOCS + p * 4 + o] = l4[o];
  }
  double cl[7];
#pragma unroll
  for (int i = 0; i < 7; ++i) {
    cl[i] = lg[4 + i] + (double)cls_b[i];
    out[O_CLS + p * 7 + i] = (float)cl[i];
  }
  double z = lg[11] + (double)cos_b[0];
  double sig = 1.0 / (1.0 + exp(-z));
  out[O_COS + p] = (float)sig;
  double pm = cl[0];
  int ai = 0;
#pragma unroll
  for (int i = 1; i < 7; ++i)
    if (cl[i] > pm) { pm = cl[i]; ai = i; }
  double mx = cl[0];
#pragma unroll
  for (int i = 1; i < 7; ++i) mx = fmax(mx, cl[i]);
  double S = 0.0;
#pragma unroll
  for (int i = 0; i < 7; ++i) S += exp(cl[i] - mx);
  double p0 = exp(cl[0] - mx) / S;
  float fg = (float)(1.0 - p0);
  const float BS[7] = {16.f, 9.f, 14.f, 21.f, 33.f, 54.f, 93.f};
  float ascale_p = BS[ai];
  // ---- pixel 0's cos (f32 cast) and ascale, recomputed redundantly ----
  double cl0[7];
#pragma unroll
  for (int i = 0; i < 7; ++i) cl0[i] = logits[4 + i] + (double)cls_b[i];
  double pm0 = cl0[0];
  int ai0 = 0;
#pragma unroll
  for (int i = 1; i < 7; ++i)
    if (cl0[i] > pm0) { pm0 = cl0[i]; ai0 = i; }
  float ascale0 = BS[ai0];
  double z0 = logits[11] + (double)cos_b[0];
  float a0 = (float)(1.0 / (1.0 + exp(-z0)));
  // ---- roi(p) ----
  if (a0 == 0.0f) a0 = __fadd_rn(a0, 1e-5f);
  float t1 = __fmul_rn(a0, a0);
  float t2 = __fdiv_rn(1.0f, t1);
  float t3 = __fsub_rn(t2, 1.0f);
  float anchor_h = __fmul_rn(ascale0, sqrt32(t3));
  float anchor_w = ascale_p;
  float ay = __fadd_rn((float)(p >> 7) * 8.0f, 4.0f);
  float ax = __fadd_rn((float)(p & 127) * 8.0f, 4.0f);
  float A0 = __fsub_rn(ay, __fmul_rn(0.5f, anchor_h));
  float A1 = __fsub_rn(ax, __fmul_rn(0.5f, anchor_w));
  float A2 = __fadd_rn(ay, __fmul_rn(0.5f, anchor_h));
  float A3 = __fadd_rn(ax, __fmul_rn(0.5f, anchor_w));
  *(float4*)&out[O_ANCHOR + p * 4] = make_float4(A0, A1, A2, A3);
  float hA = __fsub_rn(A2, A0), wA = __fsub_rn(A3, A1);
  float cy = __fadd_rn(A0, __fmul_rn(0.5f, hA));
  float cx = __fadd_rn(A1, __fmul_rn(0.5f, wA));
  float ncy = __fadd_rn(__fmul_rn(l4[0], hA), cy);
  float ncx = __fadd_rn(__fmul_rn(l4[1], wA), cx);
  float nh = __fmul_rn(exp32(l4[2]), hA);
  float nw = __fmul_rn(exp32(l4[3]), wA);
  float b0 = __fsub_rn(ncy, __fmul_rn(0.5f, nh));
  float b1 = __fsub_rn(ncx, __fmul_rn(0.5f, nw));
  float b2 = __fadd_rn(ncy, __fmul_rn(0.5f, nh));
  float b3 = __fadd_rn(ncx, __fmul_rn(0.5f, nw));
  float IH = (float)img_h[0], IW = (float)img_w[0];
  b0 = fminf(fmaxf(b0, 0.f), IH);
  b1 = fminf(fmaxf(b1, 0.f), IW);
  b2 = fminf(fmaxf(b2, 0.f), IH);
  b3 = fminf(fmaxf(b3, 0.f), IW);
  *(float4*)&roi[p * 4] = make_float4(b0, b1, b2, b3);
  float hs = __fsub_rn(b2, b0), wd = __fsub_rn(b3, b1);
  bool valid = (ai > 0) && (hs >= 16.f) && (wd >= 16.f);
  scores32[p] = valid ? fg : -INFINITY;
}

// ----- exact rank-selection (same key order as the old stable sort) ----------
__global__ __launch_bounds__(256) void rank_kernel(
    const float* __restrict__ scores32, const float* __restrict__ roi,
    float* __restrict__ out, float* __restrict__ cand, float* __restrict__ tops) {
  __shared__ unsigned long long kt[2048];
  int tid = threadIdx.x;
  int i = blockIdx.x * 256 + tid;           // owned element
  unsigned u = __float_as_uint(scores32[i]);
  u = (u & 0x80000000u) ? ~u : (u | 0x80000000u);
  unsigned long long mykey = ((unsigned long long)u << 32) | (unsigned)(16383 - i);
  int rank = 0;
  for (int t0 = 0; t0 < 16384; t0 += 2048) {
    __syncthreads();
#pragma unroll
    for (int s = 0; s < 8; ++s) {
      int j = t0 + s * 256 + tid;
      unsigned uj = __float_as_uint(scores32[j]);
      uj = (uj & 0x80000000u) ? ~uj : (uj | 0x80000000u);
      kt[s * 256 + tid] = ((unsigned long long)uj << 32) | (unsigned)(16383 - j);
    }
    __syncthreads();
    for (int t = 0; t < 2048; ++t)
      rank += (kt[t] > mykey) ? 1 : 0;
  }
  if (rank < NPRE) {
    float s = scores32[i];
    float4 b = make_float4(0.f, 0.f, 0.f, 0.f);
    if (isfinite(s)) b = *(const float4*)&roi[i * 4];
    ((float4*)(out + O_OLD))[rank] = b;
    ((float4*)cand)[rank] = b;
    tops[rank] = s;
  }
}

// ----- NMS stage 1: whole-GPU pairwise suppression mask ----------------------
__global__ __launch_bounds__(64) void nms_mask_kernel(
    const float* __restrict__ cand, unsigned long long* __restrict__ mask) {
  __shared__ float cy0[64], cx0[64], cy1[64], cx1[64], car[64];
  int bw = blockIdx.x;   // column word
  int bj = blockIdx.y;   // row block
  int t = threadIdx.x;
  int c = bw * 64 + t;
  if (c < NPRE) {
    float4 b = ((const float4*)cand)[c];
    cy0[t] = b.x; cx0[t] = b.y; cy1[t] = b.z; cx1[t] = b.w;
    car[t] = __fmul_rn(__fsub_rn(b.z, b.x), __fsub_rn(b.w, b.y));
  } else {
    cy0[t] = 0.f; cx0[t] = 0.f; cy1[t] = 0.f; cx1[t] = 0.f; car[t] = 0.f;
  }
  __syncthreads();
  int r = bj * 64 + t;
  if (r >= NPRE) return;
  float4 rb = ((const float4*)cand)[r];
  float rar = __fmul_rn(__fsub_rn(rb.z, rb.x), __fsub_rn(rb.w, rb.y));
  unsigned long long bits = 0;
#pragma unroll 4
  for (int b = 0; b < 64; ++b) {
    int j = bw * 64 + b;
    float yy0 = fmaxf(cy0[b], rb.x), xx0 = fmaxf(cx0[b], rb.y);
    float yy1 = fminf(cy1[b], rb.z), xx1 = fminf(cx1[b], rb.w);
    float inter = __fmul_rn(fmaxf(__fsub_rn(yy1, yy0), 0.f),
                            fmaxf(__fsub_rn(xx1, xx0), 0.f));
    float den = __fadd_rn(__fsub_rn(__fadd_rn(car[b], rar), inter), 1e-9f);
    float iou = __fdiv_rn(inter, den);
    if (j > r && j < NPRE && iou > 0.7f)
      bits |= 1ull << b;
  }
  mask[(size_t)r * NMW + bw] = bits;
}

// ----- NMS stage 2: tiny serial reduce over the bitmask ----------------------
__global__ __launch_bounds__(128) void nms_reduce_kernel(
    const float* __restrict__ cand, const float* __restrict__ tops,
    const unsigned long long* __restrict__ mask, float* __restrict__ out) {
  __shared__ unsigned long long remv[NMW];
  __shared__ int red2[2];
  int tid = threadIdx.x;
  int lane = tid & 63, wid = tid >> 6;
  if (tid < NMW) remv[tid] = 0ull;
  __syncthreads();
  int kdone = NPOST;
  for (int k = 0; k < NPOST; ++k) {
    int cnd = 0x7FFFFFFF;
    if (tid < NMW) {
      unsigned long long avail = ~remv[tid];
      if (tid == NMW - 1) avail &= (1ull << (NPRE - (NMW - 1) * 64)) - 1;
      if (avail) cnd = (tid << 6) + (int)__builtin_ctzll(avail);
    }
#pragma unroll
    for (int off = 32; off; off >>= 1) {
      int o = __shfl_xor(cnd, off, 64);
      cnd = min(cnd, o);
    }
    if (lane == 0) red2[wid] = cnd;
    __syncthreads();
    int pick = min(red2[0], red2[1]);
    bool valid = (pick != 0x7FFFFFFF) && (tops[pick] != -INFINITY);
    if (!valid) { kdone = k; break; }
    if (tid == 0) {
      float4 b = ((const float4*)cand)[pick];
      out[O_ROIS + k * 4 + 0] = b.x;
      out[O_ROIS + k * 4 + 1] = b.y;
      out[O_ROIS + k * 4 + 2] = b.z;
      out[O_ROIS + k * 4 + 3] = b.w;
      out[O_RSC + k] = tops[pick];
    }
    if (tid < NMW) {
      unsigned long long m = mask[(size_t)pick * NMW + tid];
      if (tid == (pick >> 6)) m |= 1ull << (pick & 63);
      remv[tid] |= m;
    }
    __syncthreads();
  }
  for (int t = kdone + tid; t < NPOST; t += 128) {
    out[O_ROIS + t * 4 + 0] = 0.f;
    out[O_ROIS + t * 4 + 1] = 0.f;
    out[O_ROIS + t * 4 + 2] = 0.f;
    out[O_ROIS + t * 4 + 3] = 0.f;
    out[O_RSC + t] = 0.f;
  }
  for (int t = tid; t < NPOST; t += 128) out[O_RIDX + t] = 0.f;
}

extern "C" void kernel_launch(void* const* d_in, const int* in_sizes, int n_in,
                              void* d_out, int out_size, void* d_ws, size_t ws_size,
                              hipStream_t stream) {
  (void)in_sizes; (void)n_in; (void)out_size; (void)ws_size;
  const float* x      = (const float*)d_in[0];
  const int*   skel   = (const int*)d_in[1];
  const float* conv_w = (const float*)d_in[2];
  const float* conv_b = (const float*)d_in[3];
  const float* loc_w  = (const float*)d_in[4];
  const float* loc_b  = (const float*)d_in[5];
  const float* cls_w  = (const float*)d_in[6];
  const float* cls_b  = (const float*)d_in[7];
  const float* cos_w  = (const float*)d_in[8];
  const float* cos_b  = (const float*)d_in[9];
  const int*   img_h  = (const int*)d_in[10];
  const int*   img_w  = (const int*)d_in[11];
  float* out = (float*)d_out;
  float* ws  = (float*)d_ws;

  float*  wt2      = ws + WS_WT;
  int*    list     = (int*)(ws + WS_LIST);
  int*    nact     = (int*)(ws + WS_NACT);
  unsigned long long* nmsmask = (unsigned long long*)(ws + WS_MASK);
  double* logits   = (double*)(ws + WS_LOG);
  float*  roi      = ws + WS_ROI;
  float*  scores32 = ws + WS_SC32;
  float*  cand     = ws + WS_CAND;
  float*  tops     = ws + WS_TOPS;

  hipLaunchKernelGGL(prep_kernel, dim3(1024), dim3(256), 0, stream, conv_w, wt2,
                     logits, skel, list, nact);
  hipLaunchKernelGGL(conv_mfma_kernel, dim3(2048), dim3(256), 0, stream, x, wt2,
                     conv_b, loc_w, cls_w, cos_w, list, nact, logits);
  hipLaunchKernelGGL(finroi_kernel, dim3(64), dim3(256), 0, stream, logits, loc_b,
                     cls_b, cos_b, img_h, img_w, out, roi, scores32);
  hipLaunchKernelGGL(rank_kernel, dim3(64), dim3(256), 0, stream, scores32, roi, out,
                     cand, tops);
  hipLaunchKernelGGL(nms_mask_kernel, dim3(NMW, NMW), dim3(64), 0, stream, cand,
                     nmsmask);
  hipLaunchKernelGGL(nms_reduce_kernel, dim3(1), dim3(128), 0, stream, cand, tops,
                     nmsmask, out);
}

// Round 14
// 1392.244 us; speedup vs baseline: 1.0091x; 1.0091x over previous
//
#include <hip/hip_runtime.h>
#include <math.h>

#define HH 128
#define WW 128
#define CIN 512
#define NPIX 16384
#define NPRE 6000
#define NPOST 300
#define NMW 94          // u64 words per mask row: ceil(6000/64)

// workspace offsets (floats; LOG region doubles, MASK region u64, 8B-aligned)
#define WS_WT     0ull                        // 2359296 floats (f32 wt2)
#define WS_LIST   2359296ull                  // 16384 ints
#define WS_NACT   2375680ull                  // 1 int
#define WS_MASK   2375684ull                  // 6000*94 u64 = 1128000 floats
#define WS_LOG    4718592ull                  // 16384*12 doubles
#define WS_ROI    5160960ull                  // 16384*4
#define WS_SC32   5226496ull                  // 16384
#define WS_CAND   5242880ull                  // 6000*4
#define WS_TOPS   5266880ull                  // 6000

// d_out offsets (floats), concatenated tuple in return order
#define O_LOCS   0
#define O_ROIS   65536
#define O_RIDX   66736
#define O_ANCHOR 67036
#define O_CLS    132572
#define O_COS    247260
#define O_RSC    263644
#define O_OLD    263944

typedef double d4 __attribute__((ext_vector_type(4)));

__device__ __forceinline__ float exp32(float x) { return (float)exp((double)x); }
__device__ __forceinline__ float sqrt32(float x) { return (float)sqrt((double)x); }

// ---- fused prep: blocks 0..575 wt transpose+permute; 576..1022 zero logits;
// ---- block 1023 builds the compacted active-pixel list ----------------------
__global__ __launch_bounds__(256) void prep_kernel(
    const float* __restrict__ w, float* __restrict__ wt2,
    double* __restrict__ logits, const int* __restrict__ mask,
    int* __restrict__ list, int* __restrict__ nact) {
  int b = blockIdx.x;
  int tid = threadIdx.x;
  if (b < 576) {
    // wt: w[m][c][k] (f32) -> wt2[(c*9+k)][g*64 + (m%16)*4 + m/16]
    __shared__ float t[64][65];
    int ck0 = (b % 72) * 64;
    int m0  = (b / 72) * 64;
    int j  = tid & 63;
    int i0 = tid >> 6;
#pragma unroll
    for (int ii = 0; ii < 16; ++ii) {
      int i = i0 + ii * 4;
      t[i][j] = w[(size_t)(m0 + i) * 4608 + ck0 + j];
    }
    __syncthreads();
    int jp = ((j & 15) << 2) | (j >> 4);
#pragma unroll
    for (int ii = 0; ii < 16; ++ii) {
      int jj = i0 + ii * 4;
      wt2[(size_t)(ck0 + jj) * 512 + m0 + jp] = t[j][jj];
    }
  } else if (b < 1023) {
    // zero logits: 196608 doubles, grid-stride over 447 blocks
    int i = (b - 576) * 256 + tid;
    const int stride = 447 * 256;
    for (; i < NPIX * 12; i += stride) logits[i] = 0.0;
  } else {
    // alist: deterministic row-major compaction, 256 threads x 64 pixels
    __shared__ int sc[256];
    int base = tid << 6;
    int cnt = 0;
    for (int i = 0; i < 64; ++i) cnt += (mask[base + i] != 0);
    sc[tid] = cnt;
    __syncthreads();
    for (int off = 1; off < 256; off <<= 1) {
      int v = 0;
      if (tid >= off) v = sc[tid - off];
      __syncthreads();
      sc[tid] += v;
      __syncthreads();
    }
    int pos = sc[tid] - cnt;
    for (int i = 0; i < 64; ++i)
      if (mask[base + i] != 0) list[pos++] = base + i;
    if (tid == 255) nact[0] = sc[255];
  }
}

__device__ __forceinline__ void conv_comp2(const float* raws, const float2* bvs,
                                           const bool* valj, d4* acc) {
#pragma unroll
  for (int j = 0; j < 9; ++j) {
    float av = valj[j] ? raws[j] : 0.f;
    double a = (double)av;
    acc[0] = __builtin_amdgcn_mfma_f64_16x16x4f64(a, (double)bvs[j].x, acc[0], 0, 0, 0);
    acc[1] = __builtin_amdgcn_mfma_f64_16x16x4f64(a, (double)bvs[j].y, acc[1], 0, 0, 0);
  }
}

// ------- implicit-GEMM conv via fp64 MFMA 16x16x4 + fused heads --------------
// R9 body, but wave = 16 pixels x 32 OUTCH (2 frags) -> 2x work items ->
// 8 working blocks/CU (R8 evidence: 8 blocks/CU ran at 66% MfmaUtil vs 58% at
// 4). wt2's jp-permutation makes the 2 frags' B values ADJACENT: column =
// g64*64 + (col<<2) + (g32&1)*2 + nf -> one float2 load covers both frags.
// Runtime-balanced XCD swizzle at tile granularity unchanged. Head partials
// are now 16-way f64 atomicAdd (reassociation only).
__global__ __launch_bounds__(256, 2) void conv_mfma_kernel(
    const float* __restrict__ x, const float* __restrict__ wt2,
    const float* __restrict__ bias, const float* __restrict__ loc_w,
    const float* __restrict__ cls_w, const float* __restrict__ cos_w,
    const int* __restrict__ list, const int* __restrict__ nact,
    double* __restrict__ logits) {
  int tid = threadIdx.x;
  int lane = tid & 63;
  int wv = tid >> 6;                  // wave 0..3
  int n = nact[0];
  int ntg = (n + 63) >> 6;            // active tile-groups (4 x 16-pixel tiles)
  int total = ntg << 4;               // work items: w = tg*16 + g32, g32 0..15
  int lin = blockIdx.x;
  int xcd = lin & 7;
  int slot = lin >> 3;
  int wpx = (total + 7) >> 3;         // work items per XCD
  int w = xcd * wpx + slot;
  if (slot >= wpx || w >= total) return;   // block-uniform exit
  int tg = w >> 4;                    // tile-group (contiguous range per XCD)
  int g32 = w & 15;                   // 32-outch group
  int m0 = g32 << 5;                  // outch base
  int tile = tg * 4 + wv;             // 16-pixel tile
  if (tile * 16 >= n) return;         // tail: wave-uniform exit, no barriers
  int col = lane & 15;
  int kk = lane >> 4;

  // --- probe the D layout: rowmap[r], colmap[r] per lane register ---
  d4 zz = (d4){0.0, 0.0, 0.0, 0.0};
  double pa1 = (kk == 0) ? (double)col : 0.0;   // A[m][0] = m
  double pb1 = (kk == 0) ? 1.0 : 0.0;           // B[0][n] = 1
  d4 rp = __builtin_amdgcn_mfma_f64_16x16x4f64(pa1, pb1, zz, 0, 0, 0);
  double pa2 = (kk == 0) ? 1.0 : 0.0;           // A[m][0] = 1
  double pb2 = (kk == 0) ? (double)col : 0.0;   // B[0][n] = n
  d4 cp = __builtin_amdgcn_mfma_f64_16x16x4f64(pa2, pb2, zz, 0, 0, 0);
  int rowmap[4], colmap[4];
#pragma unroll
  for (int r = 0; r < 4; ++r) {
    rowmap[r] = (int)rp[r];
    colmap[r] = (int)cp[r];
  }

  int slotp = tile * 16 + col;        // A-row pixel for this lane
  int p = (slotp < n) ? list[slotp] : -1;
  bool pv = (p >= 0);
  int py = p >> 7, px = p & 127;

  // per-lane tap offsets + validity, hoisted out of the K loop
  int offj[9];
  bool valj[9];
#pragma unroll
  for (int j = 0; j < 9; ++j) {
    int dy = j / 3 - 1, dx = j % 3 - 1;
    int yy = py + dy, xx = px + dx;
    bool v = pv && (yy >= 0) && (yy < HH) && (xx >= 0) && (xx < WW);
    valj[j] = v;
    offj[j] = v ? (yy * WW + xx) : 0;
  }

  d4 acc[2];
#pragma unroll
  for (int nf = 0; nf < 2; ++nf) acc[nf] = (d4){0.0, 0.0, 0.0, 0.0};

  const float* xk = x + (size_t)kk * NPIX;
  // B column: within the 64-group (m0 & ~63), frag nf at jp = (col<<2) +
  // (g32&1)*2 + nf  -> float2 covers nf=0,1.
  const float* wk = wt2 + (size_t)(kk * 9) * 512 + (m0 & ~63) + (col << 2) +
                    ((g32 & 1) << 1);

  for (int c0 = 0; c0 < CIN; c0 += 8) {
    const float* xc0 = xk + (size_t)c0 * NPIX;
    const float* xc1 = xc0 + (size_t)4 * NPIX;
    const float* wc0 = wk + (size_t)c0 * 4608;   // c0*9*512
    const float* wc1 = wc0 + 4 * 4608;
    // batch-issue all 36 loads (18 A dwords + 18 B dwordx2), then 36 MFMAs
    float raws[18];
    float2 bvs[18];
#pragma unroll
    for (int j = 0; j < 9; ++j) {
      raws[j] = xc0[offj[j]];
      raws[9 + j] = xc1[offj[j]];
      bvs[j] = *(const float2*)(wc0 + j * 512);
      bvs[9 + j] = *(const float2*)(wc1 + j * 512);
    }
    conv_comp2(raws, bvs, valj, acc);
    conv_comp2(raws + 9, bvs + 9, valj, acc);
  }

  // Layout-independent epilogue: reg jj = D[rowmap[jj]][colmap[jj]] of the
  // 16x32 tile. bias/relu per true col, head dots per true col, 16-lane
  // reduce per kk-group, 16-way f64 atomicAdd into logits.
#pragma unroll
  for (int jj = 0; jj < 4; ++jj) {
    int cm = colmap[jj];
    float hvj[2];
#pragma unroll
    for (int nf = 0; nf < 2; ++nf) {
      float bb = bias[m0 + nf * 16 + cm];
      hvj[nf] = fmaxf(__fadd_rn((float)acc[nf][jj], bb), 0.f);
    }
    int s2 = tile * 16 + rowmap[jj];
    bool wr = (col == 0) && (s2 < n);
    int pix = wr ? list[s2] : 0;
#pragma unroll
    for (int r = 0; r < 12; ++r) {
      double t = 0.0;
#pragma unroll
      for (int nf = 0; nf < 2; ++nf) {
        int oc = m0 + nf * 16 + cm;
        float wh = (r < 4) ? loc_w[r * 512 + oc]
                           : (r < 11) ? cls_w[(r - 4) * 512 + oc] : cos_w[oc];
        t += (double)hvj[nf] * (double)wh;
      }
#pragma unroll
      for (int o = 8; o; o >>= 1) t += __shfl_xor(t, o, 16);
      if (wr) atomicAdd(&logits[(size_t)pix * 12 + r], t);
    }
  }
}

// ---- fused finalize+roi (R13, verified) -------------------------------------
__global__ __launch_bounds__(256) void finroi_kernel(
    const double* __restrict__ logits, const float* __restrict__ loc_b,
    const float* __restrict__ cls_b, const float* __restrict__ cos_b,
    const int* __restrict__ img_h, const int* __restrict__ img_w,
    float* __restrict__ out, float* __restrict__ roi,
    float* __restrict__ scores32) {
  int p = blockIdx.x * 256 + threadIdx.x;
  const double* lg = &logits[(size_t)p * 12];
  float l4[4];
#pragma unroll
  for (int o = 0; o < 4; ++o) {
    l4[o] = (float)(lg[o] + (double)loc_b[o]);
    out[O_LOCS + p * 4 + o] = l4[o];
  }
  double cl[7];
#pragma unroll
  for (int i = 0; i < 7; ++i) {
    cl[i] = lg[4 + i] + (double)cls_b[i];
    out[O_CLS + p * 7 + i] = (float)cl[i];
  }
  double z = lg[11] + (double)cos_b[0];
  double sig = 1.0 / (1.0 + exp(-z));
  out[O_COS + p] = (float)sig;
  double pm = cl[0];
  int ai = 0;
#pragma unroll
  for (int i = 1; i < 7; ++i)
    if (cl[i] > pm) { pm = cl[i]; ai = i; }
  double mx = cl[0];
#pragma unroll
  for (int i = 1; i < 7; ++i) mx = fmax(mx, cl[i]);
  double S = 0.0;
#pragma unroll
  for (int i = 0; i < 7; ++i) S += exp(cl[i] - mx);
  double p0 = exp(cl[0] - mx) / S;
  float fg = (float)(1.0 - p0);
  const float BS[7] = {16.f, 9.f, 14.f, 21.f, 33.f, 54.f, 93.f};
  float ascale_p = BS[ai];
  double cl0[7];
#pragma unroll
  for (int i = 0; i < 7; ++i) cl0[i] = logits[4 + i] + (double)cls_b[i];
  double pm0 = cl0[0];
  int ai0 = 0;
#pragma unroll
  for (int i = 1; i < 7; ++i)
    if (cl0[i] > pm0) { pm0 = cl0[i]; ai0 = i; }
  float ascale0 = BS[ai0];
  double z0 = logits[11] + (double)cos_b[0];
  float a0 = (float)(1.0 / (1.0 + exp(-z0)));
  if (a0 == 0.0f) a0 = __fadd_rn(a0, 1e-5f);
  float t1 = __fmul_rn(a0, a0);
  float t2 = __fdiv_rn(1.0f, t1);
  float t3 = __fsub_rn(t2, 1.0f);
  float anchor_h = __fmul_rn(ascale0, sqrt32(t3));
  float anchor_w = ascale_p;
  float ay = __fadd_rn((float)(p >> 7) * 8.0f, 4.0f);
  float ax = __fadd_rn((float)(p & 127) * 8.0f, 4.0f);
  float A0 = __fsub_rn(ay, __fmul_rn(0.5f, anchor_h));
  float A1 = __fsub_rn(ax, __fmul_rn(0.5f, anchor_w));
  float A2 = __fadd_rn(ay, __fmul_rn(0.5f, anchor_h));
  float A3 = __fadd_rn(ax, __fmul_rn(0.5f, anchor_w));
  *(float4*)&out[O_ANCHOR + p * 4] = make_float4(A0, A1, A2, A3);
  float hA = __fsub_rn(A2, A0), wA = __fsub_rn(A3, A1);
  float cy = __fadd_rn(A0, __fmul_rn(0.5f, hA));
  float cx = __fadd_rn(A1, __fmul_rn(0.5f, wA));
  float ncy = __fadd_rn(__fmul_rn(l4[0], hA), cy);
  float ncx = __fadd_rn(__fmul_rn(l4[1], wA), cx);
  float nh = __fmul_rn(exp32(l4[2]), hA);
  float nw = __fmul_rn(exp32(l4[3]), wA);
  float b0 = __fsub_rn(ncy, __fmul_rn(0.5f, nh));
  float b1 = __fsub_rn(ncx, __fmul_rn(0.5f, nw));
  float b2 = __fadd_rn(ncy, __fmul_rn(0.5f, nh));
  float b3 = __fadd_rn(ncx, __fmul_rn(0.5f, nw));
  float IH = (float)img_h[0], IW = (float)img_w[0];
  b0 = fminf(fmaxf(b0, 0.f), IH);
  b1 = fminf(fmaxf(b1, 0.f), IW);
  b2 = fminf(fmaxf(b2, 0.f), IH);
  b3 = fminf(fmaxf(b3, 0.f), IW);
  *(float4*)&roi[p * 4] = make_float4(b0, b1, b2, b3);
  float hs = __fsub_rn(b2, b0), wd = __fsub_rn(b3, b1);
  bool valid = (ai > 0) && (hs >= 16.f) && (wd >= 16.f);
  scores32[p] = valid ? fg : -INFINITY;
}

// ----- exact rank-selection (same key order as the old stable sort) ----------
__global__ __launch_bounds__(256) void rank_kernel(
    const float* __restrict__ scores32, const float* __restrict__ roi,
    float* __restrict__ out, float* __restrict__ cand, float* __restrict__ tops) {
  __shared__ unsigned long long kt[2048];
  int tid = threadIdx.x;
  int i = blockIdx.x * 256 + tid;           // owned element
  unsigned u = __float_as_uint(scores32[i]);
  u = (u & 0x80000000u) ? ~u : (u | 0x80000000u);
  unsigned long long mykey = ((unsigned long long)u << 32) | (unsigned)(16383 - i);
  int rank = 0;
  for (int t0 = 0; t0 < 16384; t0 += 2048) {
    __syncthreads();
#pragma unroll
    for (int s = 0; s < 8; ++s) {
      int j = t0 + s * 256 + tid;
      unsigned uj = __float_as_uint(scores32[j]);
      uj = (uj & 0x80000000u) ? ~uj : (uj | 0x80000000u);
      kt[s * 256 + tid] = ((unsigned long long)uj << 32) | (unsigned)(16383 - j);
    }
    __syncthreads();
    for (int t = 0; t < 2048; ++t)
      rank += (kt[t] > mykey) ? 1 : 0;
  }
  if (rank < NPRE) {
    float s = scores32[i];
    float4 b = make_float4(0.f, 0.f, 0.f, 0.f);
    if (isfinite(s)) b = *(const float4*)&roi[i * 4];
    ((float4*)(out + O_OLD))[rank] = b;
    ((float4*)cand)[rank] = b;
    tops[rank] = s;
  }
}

// ----- NMS stage 1: whole-GPU pairwise suppression mask ----------------------
__global__ __launch_bounds__(64) void nms_mask_kernel(
    const float* __restrict__ cand, unsigned long long* __restrict__ mask) {
  __shared__ float cy0[64], cx0[64], cy1[64], cx1[64], car[64];
  int bw = blockIdx.x;   // column word
  int bj = blockIdx.y;   // row block
  int t = threadIdx.x;
  int c = bw * 64 + t;
  if (c < NPRE) {
    float4 b = ((const float4*)cand)[c];
    cy0[t] = b.x; cx0[t] = b.y; cy1[t] = b.z; cx1[t] = b.w;
    car[t] = __fmul_rn(__fsub_rn(b.z, b.x), __fsub_rn(b.w, b.y));
  } else {
    cy0[t] = 0.f; cx0[t] = 0.f; cy1[t] = 0.f; cx1[t] = 0.f; car[t] = 0.f;
  }
  __syncthreads();
  int r = bj * 64 + t;
  if (r >= NPRE) return;
  float4 rb = ((const float4*)cand)[r];
  float rar = __fmul_rn(__fsub_rn(rb.z, rb.x), __fsub_rn(rb.w, rb.y));
  unsigned long long bits = 0;
#pragma unroll 4
  for (int b = 0; b < 64; ++b) {
    int j = bw * 64 + b;
    float yy0 = fmaxf(cy0[b], rb.x), xx0 = fmaxf(cx0[b], rb.y);
    float yy1 = fminf(cy1[b], rb.z), xx1 = fminf(cx1[b], rb.w);
    float inter = __fmul_rn(fmaxf(__fsub_rn(yy1, yy0), 0.f),
                            fmaxf(__fsub_rn(xx1, xx0), 0.f));
    float den = __fadd_rn(__fsub_rn(__fadd_rn(car[b], rar), inter), 1e-9f);
    float iou = __fdiv_rn(inter, den);
    if (j > r && j < NPRE && iou > 0.7f)
      bits |= 1ull << b;
  }
  mask[(size_t)r * NMW + bw] = bits;
}

// ----- NMS stage 2: tiny serial reduce over the bitmask ----------------------
__global__ __launch_bounds__(128) void nms_reduce_kernel(
    const float* __restrict__ cand, const float* __restrict__ tops,
    const unsigned long long* __restrict__ mask, float* __restrict__ out) {
  __shared__ unsigned long long remv[NMW];
  __shared__ int red2[2];
  int tid = threadIdx.x;
  int lane = tid & 63, wid = tid >> 6;
  if (tid < NMW) remv[tid] = 0ull;
  __syncthreads();
  int kdone = NPOST;
  for (int k = 0; k < NPOST; ++k) {
    int cnd = 0x7FFFFFFF;
    if (tid < NMW) {
      unsigned long long avail = ~remv[tid];
      if (tid == NMW - 1) avail &= (1ull << (NPRE - (NMW - 1) * 64)) - 1;
      if (avail) cnd = (tid << 6) + (int)__builtin_ctzll(avail);
    }
#pragma unroll
    for (int off = 32; off; off >>= 1) {
      int o = __shfl_xor(cnd, off, 64);
      cnd = min(cnd, o);
    }
    if (lane == 0) red2[wid] = cnd;
    __syncthreads();
    int pick = min(red2[0], red2[1]);
    bool valid = (pick != 0x7FFFFFFF) && (tops[pick] != -INFINITY);
    if (!valid) { kdone = k; break; }
    if (tid == 0) {
      float4 b = ((const float4*)cand)[pick];
      out[O_ROIS + k * 4 + 0] = b.x;
      out[O_ROIS + k * 4 + 1] = b.y;
      out[O_ROIS + k * 4 + 2] = b.z;
      out[O_ROIS + k * 4 + 3] = b.w;
      out[O_RSC + k] = tops[pick];
    }
    if (tid < NMW) {
      unsigned long long m = mask[(size_t)pick * NMW + tid];
      if (tid == (pick >> 6)) m |= 1ull << (pick & 63);
      remv[tid] |= m;
    }
    __syncthreads();
  }
  for (int t = kdone + tid; t < NPOST; t += 128) {
    out[O_ROIS + t * 4 + 0] = 0.f;
    out[O_ROIS + t * 4 + 1] = 0.f;
    out[O_ROIS + t * 4 + 2] = 0.f;
    out[O_ROIS + t * 4 + 3] = 0.f;
    out[O_RSC + t] = 0.f;
  }
  for (int t = tid; t < NPOST; t += 128) out[O_RIDX + t] = 0.f;
}

extern "C" void kernel_launch(void* const* d_in, const int* in_sizes, int n_in,
                              void* d_out, int out_size, void* d_ws, size_t ws_size,
                              hipStream_t stream) {
  (void)in_sizes; (void)n_in; (void)out_size; (void)ws_size;
  const float* x      = (const float*)d_in[0];
  const int*   skel   = (const int*)d_in[1];
  const float* conv_w = (const float*)d_in[2];
  const float* conv_b = (const float*)d_in[3];
  const float* loc_w  = (const float*)d_in[4];
  const float* loc_b  = (const float*)d_in[5];
  const float* cls_w  = (const float*)d_in[6];
  const float* cls_b  = (const float*)d_in[7];
  const float* cos_w  = (const float*)d_in[8];
  const float* cos_b  = (const float*)d_in[9];
  const int*   img_h  = (const int*)d_in[10];
  const int*   img_w  = (const int*)d_in[11];
  float* out = (float*)d_out;
  float* ws  = (float*)d_ws;

  float*  wt2      = ws + WS_WT;
  int*    list     = (int*)(ws + WS_LIST);
  int*    nact     = (int*)(ws + WS_NACT);
  unsigned long long* nmsmask = (unsigned long long*)(ws + WS_MASK);
  double* logits   = (double*)(ws + WS_LOG);
  float*  roi      = ws + WS_ROI;
  float*  scores32 = ws + WS_SC32;
  float*  cand     = ws + WS_CAND;
  float*  tops     = ws + WS_TOPS;

  hipLaunchKernelGGL(prep_kernel, dim3(1024), dim3(256), 0, stream, conv_w, wt2,
                     logits, skel, list, nact);
  hipLaunchKernelGGL(conv_mfma_kernel, dim3(4096), dim3(256), 0, stream, x, wt2,
                     conv_b, loc_w, cls_w, cos_w, list, nact, logits);
  hipLaunchKernelGGL(finroi_kernel, dim3(64), dim3(256), 0, stream, logits, loc_b,
                     cls_b, cos_b, img_h, img_w, out, roi, scores32);
  hipLaunchKernelGGL(rank_kernel, dim3(64), dim3(256), 0, stream, scores32, roi, out,
                     cand, tops);
  hipLaunchKernelGGL(nms_mask_kernel, dim3(NMW, NMW), dim3(64), 0, stream, cand,
                     nmsmask);
  hipLaunchKernelGGL(nms_reduce_kernel, dim3(1), dim3(128), 0, stream, cand, tops,
                     nmsmask, out);
}